// Round 1
// baseline (390.800 us; speedup 1.0000x reference)
//
#include <hip/hip_runtime.h>
#include <math.h>

#define NCH 48            // N*C = 16*3
#define WIN 11
#define HALO 10
#define BW 32
#define BH 32
#define IW (BW + HALO)    // 42
#define IH (BH + HALO)    // 42

struct GaussW { float g[WIN]; };

// ---------------------------------------------------------------------------
// Fused per-level SSIM kernel: one block = one 32x32 output tile of one (n,c)
// ---------------------------------------------------------------------------
__global__ __launch_bounds__(256)
void ssim_level_kernel(const float* __restrict__ X, const float* __restrict__ Y,
                       int H, int W, int outH, int outW,
                       float* __restrict__ accS2, float* __restrict__ accD,
                       GaussW gw)
{
    const int nc    = blockIdx.z;
    const int oy0   = blockIdx.y * BH;
    const int ox0   = blockIdx.x * BW;
    const int tid   = threadIdx.x;

    const float* __restrict__ Xp = X + (size_t)nc * H * W;
    const float* __restrict__ Yp = Y + (size_t)nc * H * W;

    __shared__ float sX[IH][IW + 1];   // stride 43 (odd) -> conflict-free
    __shared__ float sY[IH][IW + 1];
    __shared__ float hb[5][IH][BW];    // horizontally blurred mu1,mu2,xx,yy,xy
    __shared__ float wpart[2][4];

    // ---- load input tile (with halo); out-of-range -> 0 (never consumed) ----
    for (int l = tid; l < IH * IW; l += 256) {
        int r = l / IW, c = l - r * IW;
        int gy = oy0 + r, gx = ox0 + c;
        float xv = 0.f, yv = 0.f;
        if (gy < H && gx < W) {
            size_t idx = (size_t)gy * W + gx;
            xv = Xp[idx];
            yv = Yp[idx];
        }
        sX[r][c] = xv;
        sY[r][c] = yv;
    }
    __syncthreads();

    // ---- horizontal blur of 5 signals (products on the fly) ----
    for (int l = tid; l < IH * BW; l += 256) {
        int r = l >> 5, c = l & 31;
        float ax = 0.f, ay = 0.f, axx = 0.f, ayy = 0.f, axy = 0.f;
#pragma unroll
        for (int k = 0; k < WIN; ++k) {
            float gv = gw.g[k];
            float xv = sX[r][c + k];
            float yv = sY[r][c + k];
            ax  += gv * xv;
            ay  += gv * yv;
            axx += gv * xv * xv;
            ayy += gv * yv * yv;
            axy += gv * xv * yv;
        }
        hb[0][r][c] = ax;
        hb[1][r][c] = ay;
        hb[2][r][c] = axx;
        hb[3][r][c] = ayy;
        hb[4][r][c] = axy;
    }
    __syncthreads();

    // ---- vertical blur + SSIM math; thread handles 4 consecutive rows ----
    const float C1 = 1e-4f;     // (0.01*1)^2
    const float C2 = 9e-4f;     // (0.03*1)^2
    float locS2 = 0.f, locD = 0.f;
    const int c  = tid & 31;
    const int r0 = (tid >> 5) * 4;
#pragma unroll
    for (int rr = 0; rr < 4; ++rr) {
        int r  = r0 + rr;
        int oy = oy0 + r, ox = ox0 + c;
        if (oy < outH && ox < outW) {
            float mu1 = 0.f, mu2 = 0.f, sxx = 0.f, syy = 0.f, sxy = 0.f;
#pragma unroll
            for (int k = 0; k < WIN; ++k) {
                float gv = gw.g[k];
                mu1 += gv * hb[0][r + k][c];
                mu2 += gv * hb[1][r + k][c];
                sxx += gv * hb[2][r + k][c];
                syy += gv * hb[3][r + k][c];
                sxy += gv * hb[4][r + k][c];
            }
            float mu1sq = mu1 * mu1;
            float mu2sq = mu2 * mu2;
            float mu12  = mu1 * mu2;
            float s1  = sxx - mu1sq;
            float s2v = syy - mu2sq;
            float s12 = sxy - mu12;
            float S1 = (2.f * mu12 + C1) / (mu1sq + mu2sq + C1);
            float S2 = (2.f * s12 + C2) / (s1 + s2v + C2);
            float S  = S1 + S2;
            if (S > 2.f) S = 2.f;
            float D = sqrtf(2.f - S);
            locS2 += S2;
            locD  += D;
        }
    }

    // ---- block reduction: wave shuffle, then 4 wave partials ----
#pragma unroll
    for (int off = 32; off > 0; off >>= 1) {
        locS2 += __shfl_down(locS2, off);
        locD  += __shfl_down(locD,  off);
    }
    int wave = tid >> 6;
    if ((tid & 63) == 0) {
        wpart[0][wave] = locS2;
        wpart[1][wave] = locD;
    }
    __syncthreads();
    if (tid == 0) {
        float s = wpart[0][0] + wpart[0][1] + wpart[0][2] + wpart[0][3];
        float d = wpart[1][0] + wpart[1][1] + wpart[1][2] + wpart[1][3];
        atomicAdd(&accS2[nc], s);
        atomicAdd(&accD[nc],  d);
    }
}

// ---------------------------------------------------------------------------
// 2x2 average pool (all level sizes even -> no padding path needed)
// ---------------------------------------------------------------------------
__global__ __launch_bounds__(256)
void avgpool2_kernel(const float* __restrict__ src, float* __restrict__ dst,
                     int H, int W, int oh, int ow, int total)
{
    for (int i = blockIdx.x * blockDim.x + threadIdx.x; i < total;
         i += gridDim.x * blockDim.x) {
        int ox = i % ow;
        int t  = i / ow;
        int oy = t % oh;
        int nc = t / oh;
        const float* s = src + ((size_t)nc * H + 2 * oy) * W + 2 * ox;
        dst[i] = 0.25f * (s[0] + s[1] + s[W] + s[W + 1]);
    }
}

// ---------------------------------------------------------------------------
// zero the accumulators (ws is poisoned 0xAA before every call)
// ---------------------------------------------------------------------------
__global__ void zero_acc_kernel(float* acc, int n)
{
    int i = blockIdx.x * blockDim.x + threadIdx.x;
    if (i < n) acc[i] = 0.f;
}

// ---------------------------------------------------------------------------
// finalize: per-(n,c) weighted product over levels, mean -> scalar
// acc layout per level: [lvl*96 + 0..47] = sum S2, [lvl*96 + 48..95] = sum D
// ---------------------------------------------------------------------------
__global__ void finalize_kernel(const float* __restrict__ acc, float* __restrict__ out)
{
    int t = threadIdx.x;
    float v = 0.f;
    if (t < NCH) {
        const float w[5]   = {0.0448f, 0.2856f, 0.3001f, 0.2363f, 0.1333f};
        const float cnt[5] = {502.f * 502.f, 246.f * 246.f, 118.f * 118.f,
                              54.f * 54.f, 22.f * 22.f};
        float val = 1.f;
#pragma unroll
        for (int l = 0; l < 4; ++l) {
            float cs = acc[l * 96 + t] / cnt[l];
            cs = fmaxf(cs, 0.f);
            val *= powf(cs, w[l]);
        }
        float d = acc[4 * 96 + 48 + t] / cnt[4];
        d = fmaxf(d, 0.f);
        val *= powf(d, w[4]);
        v = val;
    }
#pragma unroll
    for (int off = 32; off > 0; off >>= 1) v += __shfl_down(v, off);
    if (t == 0) out[0] = v / (float)NCH;
}

// ---------------------------------------------------------------------------
static GaussW make_gauss()
{
    GaussW gw;
    double v[WIN], s = 0.0;
    for (int i = 0; i < WIN; ++i) {
        double c = (double)i - (WIN / 2);
        v[i] = exp(-c * c / (2.0 * 1.5 * 1.5));
        s += v[i];
    }
    for (int i = 0; i < WIN; ++i) gw.g[i] = (float)(v[i] / s);
    return gw;
}

extern "C" void kernel_launch(void* const* d_in, const int* in_sizes, int n_in,
                              void* d_out, int out_size, void* d_ws, size_t ws_size,
                              hipStream_t stream)
{
    const float* X0 = (const float*)d_in[0];
    const float* Y0 = (const float*)d_in[1];
    float* out = (float*)d_out;
    char*  ws  = (char*)d_ws;

    // accumulators: 5 levels x 96 floats (48 S2-sums + 48 D-sums)
    float* acc = (float*)ws;
    const int accN = 5 * 96;
    zero_acc_kernel<<<(accN + 255) / 256, 256, 0, stream>>>(acc, accN);

    float* pyr = (float*)(ws + 4096);
    GaussW gw = make_gauss();

    const float* curX = X0;
    const float* curY = Y0;
    float* nextbuf = pyr;
    int H = 512;

    for (int lvl = 0; lvl < 5; ++lvl) {
        int outH  = H - HALO;
        int tiles = (outH + BW - 1) / BW;
        dim3 grid(tiles, tiles, NCH);
        ssim_level_kernel<<<grid, 256, 0, stream>>>(
            curX, curY, H, H, outH, outH,
            acc + lvl * 96, acc + lvl * 96 + 48, gw);

        if (lvl < 4) {
            int oh = H / 2;
            size_t elems = (size_t)NCH * oh * oh;
            float* nX = nextbuf;
            float* nY = nX + elems;
            nextbuf   = nY + elems;
            int total = (int)elems;
            int blocks = (total + 255) / 256;
            if (blocks > 4096) blocks = 4096;
            avgpool2_kernel<<<blocks, 256, 0, stream>>>(curX, nX, H, H, oh, oh, total);
            avgpool2_kernel<<<blocks, 256, 0, stream>>>(curY, nY, H, H, oh, oh, total);
            curX = nX;
            curY = nY;
            H = oh;
        }
    }

    finalize_kernel<<<1, 64, 0, stream>>>(acc, out);
}

// Round 2
// 343.573 us; speedup vs baseline: 1.1375x; 1.1375x over previous
//
#include <hip/hip_runtime.h>
#include <math.h>

#define NCH 48            // N*C = 16*3
#define WIN 11
#define HALO 10
#define BW 32
#define BH 32
#define IW 42             // BW + HALO
#define IH 42
#define LS 44             // padded LDS row stride (mult of 4 -> 16B aligned rows)

struct GaussW { float g[WIN]; };

// ---------------------------------------------------------------------------
// Fused per-level kernel: one block = one 32x32 output tile of one (n,c).
// Does: load tile -> (optional) 2x2 avgpool emit for next level ->
// vertical blur (5 signals, register sliding window) -> horizontal blur
// (float4 LDS reads) + SSIM math -> block reduce -> atomic accumulate.
// ---------------------------------------------------------------------------
__global__ __launch_bounds__(256, 3)
void ssim_level_kernel(const float* __restrict__ X, const float* __restrict__ Y,
                       int H, int W, int outH, int outW,
                       float* __restrict__ accS2, float* __restrict__ accD,
                       float* __restrict__ poolX, float* __restrict__ poolY,
                       GaussW gw)
{
    const int nc  = blockIdx.z;
    const int oy0 = blockIdx.y * BH;
    const int ox0 = blockIdx.x * BW;
    const int tid = threadIdx.x;

    const float* __restrict__ Xp = X + (size_t)nc * H * W;
    const float* __restrict__ Yp = Y + (size_t)nc * H * W;

    __shared__ float sX[IH][LS];
    __shared__ float sY[IH][LS];
    __shared__ float vb[5][BH][LS];    // vertically blurred mu1,mu2,xx,yy,xy
    __shared__ float wpart[2][4];

    // ---- load input tile (float2 pairs); OOB -> 0 (never consumed) ----
    for (int l = tid; l < IH * 21; l += 256) {   // 42 rows x 21 float2 = 882
        int r  = l / 21, cp = l - r * 21;
        int gy = oy0 + r, gx = ox0 + 2 * cp;
        float2 xv = make_float2(0.f, 0.f), yv = xv;
        if (gy < H && gx < W) {                  // W even, gx even -> gx+1<W
            size_t idx = (size_t)gy * W + gx;
            xv = *(const float2*)(Xp + idx);
            yv = *(const float2*)(Yp + idx);
        }
        sX[r][2 * cp]     = xv.x;
        sX[r][2 * cp + 1] = xv.y;
        sY[r][2 * cp]     = yv.x;
        sY[r][2 * cp + 1] = yv.y;
    }
    __syncthreads();

    // ---- fused 2x2 avg-pool of this tile's 32x32 raw quadrant ----
    // tiles*32 == H at every level, so quadrants tile the input exactly.
    if (poolX) {
        int py = tid >> 4, px = tid & 15;
        int pH = H >> 1, pW = W >> 1;
        float vx = 0.25f * (sX[2 * py][2 * px]     + sX[2 * py][2 * px + 1] +
                            sX[2 * py + 1][2 * px] + sX[2 * py + 1][2 * px + 1]);
        float vy = 0.25f * (sY[2 * py][2 * px]     + sY[2 * py][2 * px + 1] +
                            sY[2 * py + 1][2 * px] + sY[2 * py + 1][2 * px + 1]);
        size_t o = ((size_t)nc * pH + (oy0 >> 1) + py) * pW + (ox0 >> 1) + px;
        poolX[o] = vx;
        poolY[o] = vy;
    }

    // ---- vertical blur: thread owns 4 consecutive output rows, one col ----
    for (int g = tid; g < 8 * IW; g += 256) {    // 8 row-groups x 42 cols
        int rg = g / IW, c = g - rg * IW;
        int r0 = rg * 4;
        float a0[4] = {0, 0, 0, 0}, a1[4] = {0, 0, 0, 0}, a2[4] = {0, 0, 0, 0};
        float a3[4] = {0, 0, 0, 0}, a4[4] = {0, 0, 0, 0};
#pragma unroll
        for (int i = 0; i < 14; ++i) {           // 4 outputs need 14 input rows
            float xv = sX[r0 + i][c];
            float yv = sY[r0 + i][c];
            float xx = xv * xv, yy = yv * yv, xy = xv * yv;
#pragma unroll
            for (int j = 0; j < 4; ++j) {
                int k = i - j;
                if (k >= 0 && k < WIN) {
                    float gv = gw.g[k];
                    a0[j] += gv * xv;
                    a1[j] += gv * yv;
                    a2[j] += gv * xx;
                    a3[j] += gv * yy;
                    a4[j] += gv * xy;
                }
            }
        }
#pragma unroll
        for (int j = 0; j < 4; ++j) {
            vb[0][r0 + j][c] = a0[j];
            vb[1][r0 + j][c] = a1[j];
            vb[2][r0 + j][c] = a2[j];
            vb[3][r0 + j][c] = a3[j];
            vb[4][r0 + j][c] = a4[j];
        }
    }
    __syncthreads();

    // ---- horizontal blur (float4 LDS reads) + SSIM; 4 outputs/thread ----
    const float C1 = 1e-4f, C2 = 9e-4f;
    float locS2 = 0.f, locD = 0.f;
    {
        const int r  = tid >> 3;
        const int cb = (tid & 7) * 4;
        float st[5][4];
#pragma unroll
        for (int s = 0; s < 5; ++s) {
            const float4* p = (const float4*)(&vb[s][r][cb]);
            float4 q0 = p[0], q1 = p[1], q2 = p[2], q3 = p[3];
            float w[16] = {q0.x, q0.y, q0.z, q0.w, q1.x, q1.y, q1.z, q1.w,
                           q2.x, q2.y, q2.z, q2.w, q3.x, q3.y, q3.z, q3.w};
#pragma unroll
            for (int j = 0; j < 4; ++j) {
                float acc = 0.f;
#pragma unroll
                for (int k = 0; k < WIN; ++k) acc += gw.g[k] * w[j + k];
                st[s][j] = acc;
            }
        }
        const int oy = oy0 + r;
#pragma unroll
        for (int j = 0; j < 4; ++j) {
            int ox = ox0 + cb + j;
            if (oy < outH && ox < outW) {
                float mu1 = st[0][j], mu2 = st[1][j];
                float mu1sq = mu1 * mu1, mu2sq = mu2 * mu2, mu12 = mu1 * mu2;
                float s1  = st[2][j] - mu1sq;
                float s2v = st[3][j] - mu2sq;
                float s12 = st[4][j] - mu12;
                float S1 = (2.f * mu12 + C1) / (mu1sq + mu2sq + C1);
                float S2 = (2.f * s12 + C2) / (s1 + s2v + C2);
                float S  = S1 + S2;
                if (S > 2.f) S = 2.f;
                locS2 += S2;
                locD  += sqrtf(2.f - S);
            }
        }
    }

    // ---- block reduction ----
#pragma unroll
    for (int off = 32; off > 0; off >>= 1) {
        locS2 += __shfl_down(locS2, off);
        locD  += __shfl_down(locD,  off);
    }
    int wave = tid >> 6;
    if ((tid & 63) == 0) {
        wpart[0][wave] = locS2;
        wpart[1][wave] = locD;
    }
    __syncthreads();
    if (tid == 0) {
        atomicAdd(&accS2[nc], wpart[0][0] + wpart[0][1] + wpart[0][2] + wpart[0][3]);
        atomicAdd(&accD[nc],  wpart[1][0] + wpart[1][1] + wpart[1][2] + wpart[1][3]);
    }
}

// ---------------------------------------------------------------------------
__global__ void zero_acc_kernel(float* acc, int n)
{
    int i = blockIdx.x * blockDim.x + threadIdx.x;
    if (i < n) acc[i] = 0.f;
}

// finalize: per-(n,c) weighted product over levels, mean -> scalar
// acc layout per level: [lvl*96 + 0..47] = sum S2, [lvl*96 + 48..95] = sum D
__global__ void finalize_kernel(const float* __restrict__ acc, float* __restrict__ out)
{
    int t = threadIdx.x;
    float v = 0.f;
    if (t < NCH) {
        const float w[5]   = {0.0448f, 0.2856f, 0.3001f, 0.2363f, 0.1333f};
        const float cnt[5] = {502.f * 502.f, 246.f * 246.f, 118.f * 118.f,
                              54.f * 54.f, 22.f * 22.f};
        float val = 1.f;
#pragma unroll
        for (int l = 0; l < 4; ++l) {
            float cs = fmaxf(acc[l * 96 + t] / cnt[l], 0.f);
            val *= powf(cs, w[l]);
        }
        float d = fmaxf(acc[4 * 96 + 48 + t] / cnt[4], 0.f);
        val *= powf(d, w[4]);
        v = val;
    }
#pragma unroll
    for (int off = 32; off > 0; off >>= 1) v += __shfl_down(v, off);
    if (t == 0) out[0] = v / (float)NCH;
}

// ---------------------------------------------------------------------------
static GaussW make_gauss()
{
    GaussW gw;
    double v[WIN], s = 0.0;
    for (int i = 0; i < WIN; ++i) {
        double c = (double)i - (WIN / 2);
        v[i] = exp(-c * c / (2.0 * 1.5 * 1.5));
        s += v[i];
    }
    for (int i = 0; i < WIN; ++i) gw.g[i] = (float)(v[i] / s);
    return gw;
}

extern "C" void kernel_launch(void* const* d_in, const int* in_sizes, int n_in,
                              void* d_out, int out_size, void* d_ws, size_t ws_size,
                              hipStream_t stream)
{
    const float* X0 = (const float*)d_in[0];
    const float* Y0 = (const float*)d_in[1];
    float* out = (float*)d_out;
    char*  ws  = (char*)d_ws;

    float* acc = (float*)ws;                 // 5 levels x 96 floats
    const int accN = 5 * 96;
    zero_acc_kernel<<<(accN + 255) / 256, 256, 0, stream>>>(acc, accN);

    float* pyr = (float*)(ws + 4096);
    GaussW gw = make_gauss();

    const float* curX = X0;
    const float* curY = Y0;
    float* nextbuf = pyr;
    int H = 512;

    for (int lvl = 0; lvl < 5; ++lvl) {
        int outH  = H - HALO;
        int tiles = H / BW;                  // tiles*32 == H at every level
        dim3 grid(tiles, tiles, NCH);

        float* nX = nullptr;
        float* nY = nullptr;
        if (lvl < 4) {
            int oh = H / 2;
            size_t elems = (size_t)NCH * oh * oh;
            nX = nextbuf;
            nY = nX + elems;
            nextbuf = nY + elems;
        }

        ssim_level_kernel<<<grid, 256, 0, stream>>>(
            curX, curY, H, H, outH, outH,
            acc + lvl * 96, acc + lvl * 96 + 48, nX, nY, gw);

        if (lvl < 4) {
            curX = nX;
            curY = nY;
            H >>= 1;
        }
    }

    finalize_kernel<<<1, 64, 0, stream>>>(acc, out);
}

// Round 3
// 268.215 us; speedup vs baseline: 1.4570x; 1.2810x over previous
//
#include <hip/hip_runtime.h>
#include <math.h>

#define NCH 48            // N*C = 16*3
#define WIN 11
#define HALO 10
#define BW 64             // output tile width
#define BH 32             // output tile height
#define IW 74             // BW + HALO
#define IH 42             // BH + HALO
#define LS 76             // LDS row stride in floats (76*4=304B, mult of 16)

struct GaussW { float g[WIN]; };

// vertical blur of NOUT consecutive output rows at column c (rows r0..r0+NOUT-1)
template<int NOUT>
__device__ __forceinline__ void vblur_col(const float (*sX)[LS], const float (*sY)[LS],
                                          float (*vb)[BH][LS],
                                          int r0, int c, const GaussW& gw)
{
    float a0[NOUT], a1[NOUT], a2[NOUT], a3[NOUT], a4[NOUT];
#pragma unroll
    for (int j = 0; j < NOUT; ++j) { a0[j] = a1[j] = a2[j] = a3[j] = a4[j] = 0.f; }
#pragma unroll
    for (int i = 0; i < NOUT + 10; ++i) {
        float xv = sX[r0 + i][c];
        float yv = sY[r0 + i][c];
        float xx = xv * xv, yy = yv * yv, xy = xv * yv;
#pragma unroll
        for (int j = 0; j < NOUT; ++j) {
            int k = i - j;
            if (k >= 0 && k < WIN) {
                float gv = gw.g[k];
                a0[j] += gv * xv;
                a1[j] += gv * yv;
                a2[j] += gv * xx;
                a3[j] += gv * yy;
                a4[j] += gv * xy;
            }
        }
    }
#pragma unroll
    for (int j = 0; j < NOUT; ++j) {
        vb[0][r0 + j][c] = a0[j];
        vb[1][r0 + j][c] = a1[j];
        vb[2][r0 + j][c] = a2[j];
        vb[3][r0 + j][c] = a3[j];
        vb[4][r0 + j][c] = a4[j];
    }
}

// ---------------------------------------------------------------------------
// Fused per-level kernel: one block = one 64x32 output tile of one (n,c).
// load tile -> fused 2x2 avgpool emit -> vertical blur (reg sliding window)
// -> horizontal blur (b128 LDS reads) + SSIM -> block reduce -> atomics.
// ---------------------------------------------------------------------------
__global__ __launch_bounds__(512, 4)
void ssim_level_kernel(const float* __restrict__ X, const float* __restrict__ Y,
                       int H, int W, int outH, int outW,
                       float* __restrict__ accS2, float* __restrict__ accD,
                       float* __restrict__ poolX, float* __restrict__ poolY,
                       GaussW gw)
{
    const int nc  = blockIdx.z;
    const int oy0 = blockIdx.y * BH;
    const int ox0 = blockIdx.x * BW;
    const int tid = threadIdx.x;

    const float* __restrict__ Xp = X + (size_t)nc * H * W;
    const float* __restrict__ Yp = Y + (size_t)nc * H * W;

    __shared__ __align__(16) float sX[IH][LS];
    __shared__ __align__(16) float sY[IH][LS];
    __shared__ __align__(16) float vb[5][BH][LS];  // mu1,mu2,xx,yy,xy (V-blurred)
    __shared__ float wpart[2][8];

    // ---- load input tile as float2 pairs; OOB -> 0 ----
    for (int l = tid; l < IH * 38; l += 512) {     // 42 rows x 38 float2 (covers 76)
        int r  = l / 38, cp = l - r * 38;
        int gy = oy0 + r, gx = ox0 + 2 * cp;
        float2 xv = make_float2(0.f, 0.f), yv = xv;
        if (gy < H && gx < W) {                    // W even, gx even -> gx+1 < W
            size_t idx = (size_t)gy * W + gx;
            xv = *(const float2*)(Xp + idx);
            yv = *(const float2*)(Yp + idx);
        }
        sX[r][2 * cp]     = xv.x;
        sX[r][2 * cp + 1] = xv.y;
        sY[r][2 * cp]     = yv.x;
        sY[r][2 * cp + 1] = yv.y;
    }
    __syncthreads();

    // ---- fused 2x2 avg-pool of raw 64x32 quadrant -> 32x16 pooled tile ----
    if (poolX) {
        int py = tid >> 5, px = tid & 31;          // 16 x 32
        int pH = H >> 1, pW = W >> 1;
        int ppy = (oy0 >> 1) + py, ppx = (ox0 >> 1) + px;
        if (ppy < pH && ppx < pW) {
            float vx = 0.25f * (sX[2 * py][2 * px]     + sX[2 * py][2 * px + 1] +
                                sX[2 * py + 1][2 * px] + sX[2 * py + 1][2 * px + 1]);
            float vy = 0.25f * (sY[2 * py][2 * px]     + sY[2 * py][2 * px + 1] +
                                sY[2 * py + 1][2 * px] + sY[2 * py + 1][2 * px + 1]);
            size_t o = ((size_t)nc * pH + ppy) * pW + ppx;
            poolX[o] = vx;
            poolY[o] = vy;
        }
    }

    // ---- vertical blur: 74 cols x (5 full 6-row groups + one 2-row tail) ----
    if (tid < IW * 6) {
        int rg = tid / IW, c = tid - rg * IW;
        if (rg < 5) vblur_col<6>(sX, sY, vb, rg * 6, c, gw);
        else        vblur_col<2>(sX, sY, vb, 30, c, gw);
    }
    __syncthreads();

    // ---- horizontal blur (float4 LDS reads) + SSIM; 4 outputs/thread ----
    const float C1 = 1e-4f, C2 = 9e-4f;
    float locS2 = 0.f, locD = 0.f;
    {
        const int r  = tid >> 4;                   // 0..31
        const int cb = (tid & 15) * 4;             // 0..60
        float st[5][4];
#pragma unroll
        for (int s = 0; s < 5; ++s) {
            const float4* p = (const float4*)(&vb[s][r][cb]);
            float4 q0 = p[0], q1 = p[1], q2 = p[2], q3 = p[3];
            float w[16] = {q0.x, q0.y, q0.z, q0.w, q1.x, q1.y, q1.z, q1.w,
                           q2.x, q2.y, q2.z, q2.w, q3.x, q3.y, q3.z, q3.w};
#pragma unroll
            for (int j = 0; j < 4; ++j) {
                float acc = 0.f;
#pragma unroll
                for (int k = 0; k < WIN; ++k) acc += gw.g[k] * w[j + k];
                st[s][j] = acc;
            }
        }
        const int oy = oy0 + r;
#pragma unroll
        for (int j = 0; j < 4; ++j) {
            int ox = ox0 + cb + j;
            if (oy < outH && ox < outW) {
                float mu1 = st[0][j], mu2 = st[1][j];
                float mu1sq = mu1 * mu1, mu2sq = mu2 * mu2, mu12 = mu1 * mu2;
                float s1  = st[2][j] - mu1sq;
                float s2v = st[3][j] - mu2sq;
                float s12 = st[4][j] - mu12;
                float S1 = (2.f * mu12 + C1) * __builtin_amdgcn_rcpf(mu1sq + mu2sq + C1);
                float S2 = (2.f * s12 + C2) * __builtin_amdgcn_rcpf(s1 + s2v + C2);
                float S  = S1 + S2;
                if (S > 2.f) S = 2.f;
                locS2 += S2;
                locD  += __builtin_amdgcn_sqrtf(2.f - S);
            }
        }
    }

    // ---- block reduction: wave shuffle, then 8 wave partials ----
#pragma unroll
    for (int off = 32; off > 0; off >>= 1) {
        locS2 += __shfl_down(locS2, off);
        locD  += __shfl_down(locD,  off);
    }
    if ((tid & 63) == 0) {
        wpart[0][tid >> 6] = locS2;
        wpart[1][tid >> 6] = locD;
    }
    __syncthreads();
    if (tid == 0) {
        float s = 0.f, d = 0.f;
#pragma unroll
        for (int i = 0; i < 8; ++i) { s += wpart[0][i]; d += wpart[1][i]; }
        atomicAdd(&accS2[nc], s);
        atomicAdd(&accD[nc],  d);
    }
}

// ---------------------------------------------------------------------------
__global__ void zero_acc_kernel(float* acc, int n)
{
    int i = blockIdx.x * blockDim.x + threadIdx.x;
    if (i < n) acc[i] = 0.f;
}

// finalize: per-(n,c) weighted product over levels, mean -> scalar
// acc layout per level: [lvl*96 + 0..47] = sum S2, [lvl*96 + 48..95] = sum D
__global__ void finalize_kernel(const float* __restrict__ acc, float* __restrict__ out)
{
    int t = threadIdx.x;
    float v = 0.f;
    if (t < NCH) {
        const float w[5]   = {0.0448f, 0.2856f, 0.3001f, 0.2363f, 0.1333f};
        const float cnt[5] = {502.f * 502.f, 246.f * 246.f, 118.f * 118.f,
                              54.f * 54.f, 22.f * 22.f};
        float val = 1.f;
#pragma unroll
        for (int l = 0; l < 4; ++l) {
            float cs = fmaxf(acc[l * 96 + t] / cnt[l], 0.f);
            val *= powf(cs, w[l]);
        }
        float d = fmaxf(acc[4 * 96 + 48 + t] / cnt[4], 0.f);
        val *= powf(d, w[4]);
        v = val;
    }
#pragma unroll
    for (int off = 32; off > 0; off >>= 1) v += __shfl_down(v, off);
    if (t == 0) out[0] = v / (float)NCH;
}

// ---------------------------------------------------------------------------
static GaussW make_gauss()
{
    GaussW gw;
    double v[WIN], s = 0.0;
    for (int i = 0; i < WIN; ++i) {
        double c = (double)i - (WIN / 2);
        v[i] = exp(-c * c / (2.0 * 1.5 * 1.5));
        s += v[i];
    }
    for (int i = 0; i < WIN; ++i) gw.g[i] = (float)(v[i] / s);
    return gw;
}

extern "C" void kernel_launch(void* const* d_in, const int* in_sizes, int n_in,
                              void* d_out, int out_size, void* d_ws, size_t ws_size,
                              hipStream_t stream)
{
    const float* X0 = (const float*)d_in[0];
    const float* Y0 = (const float*)d_in[1];
    float* out = (float*)d_out;
    char*  ws  = (char*)d_ws;

    float* acc = (float*)ws;                 // 5 levels x 96 floats
    const int accN = 5 * 96;
    zero_acc_kernel<<<(accN + 255) / 256, 256, 0, stream>>>(acc, accN);

    float* pyr = (float*)(ws + 4096);
    GaussW gw = make_gauss();

    const float* curX = X0;
    const float* curY = Y0;
    float* nextbuf = pyr;
    int H = 512;

    for (int lvl = 0; lvl < 5; ++lvl) {
        int outH = H - HALO;
        int gx = H / BW; if (gx == 0) gx = 1;
        int gy = H / BH;
        dim3 grid(gx, gy, NCH);

        float* nX = nullptr;
        float* nY = nullptr;
        if (lvl < 4) {
            int oh = H / 2;
            size_t elems = (size_t)NCH * oh * oh;
            nX = nextbuf;
            nY = nX + elems;
            nextbuf = nY + elems;
        }

        ssim_level_kernel<<<grid, 512, 0, stream>>>(
            curX, curY, H, H, outH, outH,
            acc + lvl * 96, acc + lvl * 96 + 48, nX, nY, gw);

        if (lvl < 4) {
            curX = nX;
            curY = nY;
            H >>= 1;
        }
    }

    finalize_kernel<<<1, 64, 0, stream>>>(acc, out);
}